// Round 1
// baseline (309.494 us; speedup 1.0000x reference)
//
#include <hip/hip_runtime.h>

// VecInt: scaling-and-squaring integration, vel [2,128,128,128,3] fp32.
// v = vel/2^7; 7x: v = v + warp(v, v)  (border-clipped trilinear).
//
// Round-6: latency-hiding restructure. rocprof showed round-5 at 22% HBM /
// 22% VALU / 0 MFMA — latency-bound. VGPR_Count=28 proves the compiler
// serialized the 8 scattered gathers (can't hold 8 results in 28 regs).
// Changes:
//   * 2 z-adjacent voxels per thread -> 16 independent gathers in flight,
//     flow load + field store become one 16B dwordx4 each.
//   * explicit gather-then-reduce phases so all loads issue before any use.
//   * batch offset folded into the 32-bit voxel offset -> saddr-form
//     global loads (SGPR base + 32b voffset), no per-lane 64-bit adds.
// Math order per voxel is identical to round-5 (absmax unchanged).

#define NVOX_PER_B (1 << 21)          // 128^3

typedef _Float16 h16;
typedef __attribute__((ext_vector_type(4))) _Float16 h16x4;   // 8 bytes
typedef __attribute__((ext_vector_type(8))) _Float16 h16x8;   // 16 bytes

// ---- shared address/weight computation --------------------------------
// ob = batch offset in voxel units (0 or 2^21), folded into off[].
__device__ __forceinline__ void tri_setup(
    int x, int y, int z, float fx, float fy, float fz, int ob,
    int* off, float* w)
{
    float lx = fminf(fmaxf((float)x + fx, 0.0f), 127.0f);
    float ly = fminf(fmaxf((float)y + fy, 0.0f), 127.0f);
    float lz = fminf(fmaxf((float)z + fz, 0.0f), 127.0f);

    float flx = floorf(lx), fly = floorf(ly), flz = floorf(lz);
    float wx1 = lx - flx, wy1 = ly - fly, wz1 = lz - flz;
    float wx0 = 1.0f - wx1, wy0 = 1.0f - wy1, wz0 = 1.0f - wz1;

    int x0 = (int)flx, y0 = (int)fly, z0 = (int)flz;
    int x1 = min(x0 + 1, 127);
    int y1 = min(y0 + 1, 127);
    int z1 = min(z0 + 1, 127);

    int xo0 = ob + (x0 << 14), xo1 = ob + (x1 << 14);
    int yo0 = y0 << 7,         yo1 = y1 << 7;

    off[0] = xo0 + yo0 + z0;  off[1] = xo0 + yo0 + z1;
    off[2] = xo0 + yo1 + z0;  off[3] = xo0 + yo1 + z1;
    off[4] = xo1 + yo0 + z0;  off[5] = xo1 + yo0 + z1;
    off[6] = xo1 + yo1 + z0;  off[7] = xo1 + yo1 + z1;

    w[0] = wx0 * wy0 * wz0;  w[1] = wx0 * wy0 * wz1;
    w[2] = wx0 * wy1 * wz0;  w[3] = wx0 * wy1 * wz1;
    w[4] = wx1 * wy0 * wz0;  w[5] = wx1 * wy0 * wz1;
    w[6] = wx1 * wy1 * wz0;  w[7] = wx1 * wy1 * wz1;
}

// ---- step 1: f32 packed vel -> fp16x4 field (fuses the /128 scale) -----
__global__ __launch_bounds__(256) void vecint_first(
    const float* __restrict__ vin, h16x4* __restrict__ vout,
    float scale, int nvox2)
{
    int t = blockIdx.x * blockDim.x + threadIdx.x;
    if (t >= nvox2) return;
    int idx = t << 1;                  // even voxel index; z = idx&127 even

    int z = idx & 127;
    int y = (idx >> 7) & 127;
    int x = (idx >> 14) & 127;
    int ob = idx & ~(NVOX_PER_B - 1);  // batch offset (voxel units)

    // coalesced flow load: 6 floats = 3x float2, always 8B-aligned
    const float2* f2 = (const float2*)vin;
    float2 p0 = f2[t * 3 + 0];
    float2 p1 = f2[t * 3 + 1];
    float2 p2 = f2[t * 3 + 2];
    float fax = p0.x * scale, fay = p0.y * scale, faz = p1.x * scale;
    float fbx = p1.y * scale, fby = p2.x * scale, fbz = p2.y * scale;

    int offA[8], offB[8]; float wA[8], wB[8];
    tri_setup(x, y, z,     fax, fay, faz, ob, offA, wA);
    tri_setup(x, y, z + 1, fbx, fby, fbz, ob, offB, wB);

    // gather phase: issue all 48 dword loads before any use
    float cA[8][3], cB[8][3];
#pragma unroll
    for (int c = 0; c < 8; ++c) {
        int q = offA[c] * 3;
        cA[c][0] = vin[q]; cA[c][1] = vin[q + 1]; cA[c][2] = vin[q + 2];
    }
#pragma unroll
    for (int c = 0; c < 8; ++c) {
        int q = offB[c] * 3;
        cB[c][0] = vin[q]; cB[c][1] = vin[q + 1]; cB[c][2] = vin[q + 2];
    }

    float oxA = 0.f, oyA = 0.f, ozA = 0.f;
    float oxB = 0.f, oyB = 0.f, ozB = 0.f;
#pragma unroll
    for (int c = 0; c < 8; ++c) {
        oxA += wA[c] * cA[c][0]; oyA += wA[c] * cA[c][1]; ozA += wA[c] * cA[c][2];
    }
#pragma unroll
    for (int c = 0; c < 8; ++c) {
        oxB += wB[c] * cB[c][0]; oyB += wB[c] * cB[c][1]; ozB += wB[c] * cB[c][2];
    }

    h16x8 o;
    o[0] = (h16)(fax + scale * oxA);
    o[1] = (h16)(fay + scale * oyA);
    o[2] = (h16)(faz + scale * ozA);
    o[3] = (h16)0.0f;
    o[4] = (h16)(fbx + scale * oxB);
    o[5] = (h16)(fby + scale * oyB);
    o[6] = (h16)(fbz + scale * ozB);
    o[7] = (h16)0.0f;
    *(h16x8*)(vout + idx) = o;
}

// ---- steps 2..6: fp16x4 -> fp16x4 --------------------------------------
__global__ __launch_bounds__(256) void vecint_mid(
    const h16x4* __restrict__ vin, h16x4* __restrict__ vout, int nvox2)
{
    int t = blockIdx.x * blockDim.x + threadIdx.x;
    if (t >= nvox2) return;
    int idx = t << 1;

    int z = idx & 127;
    int y = (idx >> 7) & 127;
    int x = (idx >> 14) & 127;
    int ob = idx & ~(NVOX_PER_B - 1);

    h16x8 f = *(const h16x8*)(vin + idx);   // 16B aligned (idx even)
    float fax = (float)f[0], fay = (float)f[1], faz = (float)f[2];
    float fbx = (float)f[4], fby = (float)f[5], fbz = (float)f[6];

    int offA[8], offB[8]; float wA[8], wB[8];
    tri_setup(x, y, z,     fax, fay, faz, ob, offA, wA);
    tri_setup(x, y, z + 1, fbx, fby, fbz, ob, offB, wB);

    // gather phase: 16 independent dwordx2 loads in flight
    h16x4 cA[8], cB[8];
#pragma unroll
    for (int c = 0; c < 8; ++c) cA[c] = vin[offA[c]];
#pragma unroll
    for (int c = 0; c < 8; ++c) cB[c] = vin[offB[c]];

    float oxA = 0.f, oyA = 0.f, ozA = 0.f;
    float oxB = 0.f, oyB = 0.f, ozB = 0.f;
#pragma unroll
    for (int c = 0; c < 8; ++c) {
        oxA += wA[c] * (float)cA[c].x;
        oyA += wA[c] * (float)cA[c].y;
        ozA += wA[c] * (float)cA[c].z;
    }
#pragma unroll
    for (int c = 0; c < 8; ++c) {
        oxB += wB[c] * (float)cB[c].x;
        oyB += wB[c] * (float)cB[c].y;
        ozB += wB[c] * (float)cB[c].z;
    }

    h16x8 o;
    o[0] = (h16)(fax + oxA); o[1] = (h16)(fay + oyA);
    o[2] = (h16)(faz + ozA); o[3] = (h16)0.0f;
    o[4] = (h16)(fbx + oxB); o[5] = (h16)(fby + oyB);
    o[6] = (h16)(fbz + ozB); o[7] = (h16)0.0f;
    *(h16x8*)(vout + idx) = o;
}

// ---- step 7: fp16x4 -> f32 packed --------------------------------------
__global__ __launch_bounds__(256) void vecint_last(
    const h16x4* __restrict__ vin, float* __restrict__ vout, int nvox2)
{
    int t = blockIdx.x * blockDim.x + threadIdx.x;
    if (t >= nvox2) return;
    int idx = t << 1;

    int z = idx & 127;
    int y = (idx >> 7) & 127;
    int x = (idx >> 14) & 127;
    int ob = idx & ~(NVOX_PER_B - 1);

    h16x8 f = *(const h16x8*)(vin + idx);
    float fax = (float)f[0], fay = (float)f[1], faz = (float)f[2];
    float fbx = (float)f[4], fby = (float)f[5], fbz = (float)f[6];

    int offA[8], offB[8]; float wA[8], wB[8];
    tri_setup(x, y, z,     fax, fay, faz, ob, offA, wA);
    tri_setup(x, y, z + 1, fbx, fby, fbz, ob, offB, wB);

    h16x4 cA[8], cB[8];
#pragma unroll
    for (int c = 0; c < 8; ++c) cA[c] = vin[offA[c]];
#pragma unroll
    for (int c = 0; c < 8; ++c) cB[c] = vin[offB[c]];

    float oxA = 0.f, oyA = 0.f, ozA = 0.f;
    float oxB = 0.f, oyB = 0.f, ozB = 0.f;
#pragma unroll
    for (int c = 0; c < 8; ++c) {
        oxA += wA[c] * (float)cA[c].x;
        oyA += wA[c] * (float)cA[c].y;
        ozA += wA[c] * (float)cA[c].z;
    }
#pragma unroll
    for (int c = 0; c < 8; ++c) {
        oxB += wB[c] * (float)cB[c].x;
        oyB += wB[c] * (float)cB[c].y;
        ozB += wB[c] * (float)cB[c].z;
    }

    // 6 floats out, 3x float2 (8B-aligned)
    float2* o2 = (float2*)vout;
    o2[t * 3 + 0] = make_float2(fax + oxA, fay + oyA);
    o2[t * 3 + 1] = make_float2(faz + ozA, fbx + oxB);
    o2[t * 3 + 2] = make_float2(fby + oyB, fbz + ozB);
}

extern "C" void kernel_launch(void* const* d_in, const int* in_sizes, int n_in,
                              void* d_out, int out_size, void* d_ws, size_t ws_size,
                              hipStream_t stream) {
    const float* vel = (const float*)d_in[0];
    float* out = (float*)d_out;

    int nvox2 = in_sizes[0] / 6;           // 2,097,152 threads (2 vox each)
    int blocks = (nvox2 + 255) / 256;      // 8192
    float s0 = 1.0f / 128.0f;              // 1 / 2^INT_STEPS

    // D = fp16 field living in the first 33.5 MB of d_out (d_out is 50.3 MB);
    // W = fp16 field in d_ws.
    h16x4* D = (h16x4*)d_out;
    h16x4* W = (h16x4*)d_ws;

    vecint_first<<<blocks, 256, 0, stream>>>(vel, D, s0, nvox2);  // 1: vel->D
    vecint_mid  <<<blocks, 256, 0, stream>>>(D, W, nvox2);        // 2: D->W
    vecint_mid  <<<blocks, 256, 0, stream>>>(W, D, nvox2);        // 3: W->D
    vecint_mid  <<<blocks, 256, 0, stream>>>(D, W, nvox2);        // 4: D->W
    vecint_mid  <<<blocks, 256, 0, stream>>>(W, D, nvox2);        // 5: W->D
    vecint_mid  <<<blocks, 256, 0, stream>>>(D, W, nvox2);        // 6: D->W
    vecint_last <<<blocks, 256, 0, stream>>>(W, out, nvox2);      // 7: W->out (f32)
}

// Round 2
// 302.506 us; speedup vs baseline: 1.0231x; 1.0231x over previous
//
#include <hip/hip_runtime.h>

// VecInt: scaling-and-squaring integration, vel [2,128,128,128,3] fp32.
// v = vel/2^7; 7x: v = v + warp(v, v)  (border-clipped trilinear).
//
// Round-7: round-5 proven skeleton (1 voxel/thread, 7 launches, fp16x4
// padded intermediates) + ONE change: chunked XCD block swizzle.
// Round-6 post-mortem: 2 vox/thread halved TLP without batching gathers
// (VGPR stayed 48) -> regressed 289->309us.  Reverted.
// Round-5 counters: 22% HBM / 22% VALU / 0 MFMA / occ 68% -> latency-bound.
// Theory: the 8 corner gathers have ~8-way inter-block reuse, but y-neighbor
// blocks (bid+-1) and x-neighbor blocks (bid+-64) land on DIFFERENT XCDs
// under round-robin dispatch, so every reuse misses the local L2 and is
// served by L3 (~500-700cy).  Chunked remap gives each XCD a contiguous
// 32-x-slice slab: gather reuse becomes L2-resident (~200cy).
// 16384 blocks % 8 == 0 -> (bid&7)*2048 + (bid>>3) is bijective.

#define NVOX_PER_B (1 << 21)          // 128^3
#define NXCD 8

typedef _Float16 h16;
typedef __attribute__((ext_vector_type(4))) _Float16 h16x4;   // 8 bytes

__device__ __forceinline__ int swz_idx(int nthreads_valid)
{
    // chunked XCD swizzle: contiguous 1/8 of the grid per XCD
    int nb = gridDim.x;                 // 16384, divisible by 8
    int chunk = nb >> 3;
    int bid = blockIdx.x;
    int newbid = (bid & (NXCD - 1)) * chunk + (bid >> 3);
    return newbid * blockDim.x + threadIdx.x;
}

// ---- shared address/weight computation --------------------------------
__device__ __forceinline__ void tri_setup(
    int x, int y, int z, float fx, float fy, float fz,
    int* off, float* w)     // off[8] in voxel units (unscaled), w[8]
{
    float lx = fminf(fmaxf((float)x + fx, 0.0f), 127.0f);
    float ly = fminf(fmaxf((float)y + fy, 0.0f), 127.0f);
    float lz = fminf(fmaxf((float)z + fz, 0.0f), 127.0f);

    float flx = floorf(lx), fly = floorf(ly), flz = floorf(lz);
    float wx1 = lx - flx, wy1 = ly - fly, wz1 = lz - flz;
    float wx0 = 1.0f - wx1, wy0 = 1.0f - wy1, wz0 = 1.0f - wz1;

    int x0 = (int)flx, y0 = (int)fly, z0 = (int)flz;
    int x1 = min(x0 + 1, 127);
    int y1 = min(y0 + 1, 127);
    int z1 = min(z0 + 1, 127);

    off[0] = (x0 << 14) + (y0 << 7) + z0;
    off[1] = (x0 << 14) + (y0 << 7) + z1;
    off[2] = (x0 << 14) + (y1 << 7) + z0;
    off[3] = (x0 << 14) + (y1 << 7) + z1;
    off[4] = (x1 << 14) + (y0 << 7) + z0;
    off[5] = (x1 << 14) + (y0 << 7) + z1;
    off[6] = (x1 << 14) + (y1 << 7) + z0;
    off[7] = (x1 << 14) + (y1 << 7) + z1;
    w[0] = wx0 * wy0 * wz0;  w[1] = wx0 * wy0 * wz1;
    w[2] = wx0 * wy1 * wz0;  w[3] = wx0 * wy1 * wz1;
    w[4] = wx1 * wy0 * wz0;  w[5] = wx1 * wy0 * wz1;
    w[6] = wx1 * wy1 * wz0;  w[7] = wx1 * wy1 * wz1;
}

__device__ __forceinline__ void sample_h4(
    const h16x4* __restrict__ vb, const int* off, const float* w,
    float& ox, float& oy, float& oz)
{
    ox = 0.0f; oy = 0.0f; oz = 0.0f;
#pragma unroll
    for (int c = 0; c < 8; ++c) {
        h16x4 cv = vb[off[c]];
        ox += w[c] * (float)cv.x;
        oy += w[c] * (float)cv.y;
        oz += w[c] * (float)cv.z;
    }
}

// ---- step 1: f32 packed vel -> fp16x4 field (fuses the /128 scale) -----
__global__ __launch_bounds__(256) void vecint_first(
    const float* __restrict__ vin, h16x4* __restrict__ vout,
    float scale, int nvox)
{
    int idx = swz_idx(nvox);
    if (idx >= nvox) return;

    int z = idx & 127;
    int y = (idx >> 7) & 127;
    int x = (idx >> 14) & 127;
    int b = idx >> 21;

    int base = idx * 3;
    float fx = vin[base + 0] * scale;
    float fy = vin[base + 1] * scale;
    float fz = vin[base + 2] * scale;

    int off[8]; float w[8];
    tri_setup(x, y, z, fx, fy, fz, off, w);

    const float* vb = vin + (size_t)b * (NVOX_PER_B * 3);
    float ox = 0.0f, oy = 0.0f, oz = 0.0f;
#pragma unroll
    for (int c = 0; c < 8; ++c) {
        const float* p = vb + (size_t)off[c] * 3;
        ox += w[c] * p[0]; oy += w[c] * p[1]; oz += w[c] * p[2];
    }

    h16x4 o;
    o.x = (h16)(fx + scale * ox);
    o.y = (h16)(fy + scale * oy);
    o.z = (h16)(fz + scale * oz);
    o.w = (h16)0.0f;
    vout[idx] = o;
}

// ---- steps 2..6: fp16x4 -> fp16x4 --------------------------------------
__global__ __launch_bounds__(256) void vecint_mid(
    const h16x4* __restrict__ vin, h16x4* __restrict__ vout, int nvox)
{
    int idx = swz_idx(nvox);
    if (idx >= nvox) return;

    int z = idx & 127;
    int y = (idx >> 7) & 127;
    int x = (idx >> 14) & 127;
    int b = idx >> 21;

    h16x4 f = vin[idx];
    float fx = (float)f.x, fy = (float)f.y, fz = (float)f.z;

    int off[8]; float w[8];
    tri_setup(x, y, z, fx, fy, fz, off, w);

    const h16x4* vb = vin + ((size_t)b << 21);
    float ox, oy, oz;
    sample_h4(vb, off, w, ox, oy, oz);

    h16x4 o;
    o.x = (h16)(fx + ox);
    o.y = (h16)(fy + oy);
    o.z = (h16)(fz + oz);
    o.w = (h16)0.0f;
    vout[idx] = o;
}

// ---- step 7: fp16x4 -> f32 packed --------------------------------------
__global__ __launch_bounds__(256) void vecint_last(
    const h16x4* __restrict__ vin, float* __restrict__ vout, int nvox)
{
    int idx = swz_idx(nvox);
    if (idx >= nvox) return;

    int z = idx & 127;
    int y = (idx >> 7) & 127;
    int x = (idx >> 14) & 127;
    int b = idx >> 21;

    h16x4 f = vin[idx];
    float fx = (float)f.x, fy = (float)f.y, fz = (float)f.z;

    int off[8]; float w[8];
    tri_setup(x, y, z, fx, fy, fz, off, w);

    const h16x4* vb = vin + ((size_t)b << 21);
    float ox, oy, oz;
    sample_h4(vb, off, w, ox, oy, oz);

    int base = idx * 3;
    vout[base + 0] = fx + ox;
    vout[base + 1] = fy + oy;
    vout[base + 2] = fz + oz;
}

extern "C" void kernel_launch(void* const* d_in, const int* in_sizes, int n_in,
                              void* d_out, int out_size, void* d_ws, size_t ws_size,
                              hipStream_t stream) {
    const float* vel = (const float*)d_in[0];
    float* out = (float*)d_out;

    int nvox = in_sizes[0] / 3;            // 4,194,304 voxels (2 batches)
    int blocks = (nvox + 255) / 256;       // 16384 (divisible by 8)
    float s0 = 1.0f / 128.0f;              // 1 / 2^INT_STEPS

    // D = fp16 field living in the first 33.5 MB of d_out (d_out is 50.3 MB);
    // W = fp16 field in d_ws.
    h16x4* D = (h16x4*)d_out;
    h16x4* W = (h16x4*)d_ws;

    vecint_first<<<blocks, 256, 0, stream>>>(vel, D, s0, nvox);   // 1: vel->D
    vecint_mid  <<<blocks, 256, 0, stream>>>(D, W, nvox);         // 2: D->W
    vecint_mid  <<<blocks, 256, 0, stream>>>(W, D, nvox);         // 3: W->D
    vecint_mid  <<<blocks, 256, 0, stream>>>(D, W, nvox);         // 4: D->W
    vecint_mid  <<<blocks, 256, 0, stream>>>(W, D, nvox);         // 5: W->D
    vecint_mid  <<<blocks, 256, 0, stream>>>(D, W, nvox);         // 6: D->W
    vecint_last <<<blocks, 256, 0, stream>>>(W, out, nvox);       // 7: W->out (f32)
}

// Round 3
// 265.924 us; speedup vs baseline: 1.1638x; 1.1376x over previous
//
#include <hip/hip_runtime.h>

// VecInt: scaling-and-squaring integration, vel [2,128,128,128,3] fp32.
// v = vel/2^7; 7x: v = v + warp(v, v)  (border-clipped trilinear).
//
// Round-8: 1 voxel/thread (round-5 TLP) + BATCHED gathers + z-pair loads.
// Evidence trail:
//   r5/r7: VGPR=28 -> compiler serializes the 8 gathers into ~4 wait
//          epochs (28 regs can't hold 16 data regs + addresses).
//   r6:    batched gathers at 2 vox/thread cut per-voxel cost 27%
//          (34.2us-eq vs 46.5us) but halved TLP -> net loss. So: batch at
//          1 vox/thread.
//   r7:    XCD swizzle halved FETCH_SIZE (48.8->25.7 MB/pass) -> keep it;
//          gathers are L2-resident now, only the epoch count is left.
// New in r8:
//   * z-corner pair (z0, z0+1) is 16B contiguous in the fp16x4 field ->
//     ONE dwordx4 per (x,y) corner pair: 4 gathers instead of 8.
//     wz1==0 exactly when z0==127 (clip), so the hi half is weight-0;
//     16B past each field is zeroed once so it can never be NaN.
//   * explicit load-all-then-reduce + __launch_bounds__(256,4) so the
//     allocator can keep all 4 pair results in flight (one wait epoch).

#define NVOX_PER_B (1 << 21)          // 128^3
#define NXCD 8

typedef _Float16 h16;
typedef __attribute__((ext_vector_type(4))) _Float16 h16x4;   // 8 bytes
typedef __attribute__((ext_vector_type(8))) _Float16 h16x8;   // 16 bytes

__device__ __forceinline__ int swz_idx()
{
    // chunked XCD swizzle: contiguous 1/8 of the grid per XCD (16384%8==0)
    int nb = gridDim.x;
    int chunk = nb >> 3;
    int bid = blockIdx.x;
    int newbid = (bid & (NXCD - 1)) * chunk + (bid >> 3);
    return newbid * blockDim.x + threadIdx.x;
}

// ---- full 8-corner setup (f32 first pass) ------------------------------
__device__ __forceinline__ void tri_setup(
    int x, int y, int z, float fx, float fy, float fz,
    int* off, float* w)
{
    float lx = fminf(fmaxf((float)x + fx, 0.0f), 127.0f);
    float ly = fminf(fmaxf((float)y + fy, 0.0f), 127.0f);
    float lz = fminf(fmaxf((float)z + fz, 0.0f), 127.0f);

    float flx = floorf(lx), fly = floorf(ly), flz = floorf(lz);
    float wx1 = lx - flx, wy1 = ly - fly, wz1 = lz - flz;
    float wx0 = 1.0f - wx1, wy0 = 1.0f - wy1, wz0 = 1.0f - wz1;

    int x0 = (int)flx, y0 = (int)fly, z0 = (int)flz;
    int x1 = min(x0 + 1, 127);
    int y1 = min(y0 + 1, 127);
    int z1 = min(z0 + 1, 127);

    off[0] = (x0 << 14) + (y0 << 7) + z0;
    off[1] = (x0 << 14) + (y0 << 7) + z1;
    off[2] = (x0 << 14) + (y1 << 7) + z0;
    off[3] = (x0 << 14) + (y1 << 7) + z1;
    off[4] = (x1 << 14) + (y0 << 7) + z0;
    off[5] = (x1 << 14) + (y0 << 7) + z1;
    off[6] = (x1 << 14) + (y1 << 7) + z0;
    off[7] = (x1 << 14) + (y1 << 7) + z1;
    w[0] = wx0 * wy0 * wz0;  w[1] = wx0 * wy0 * wz1;
    w[2] = wx0 * wy1 * wz0;  w[3] = wx0 * wy1 * wz1;
    w[4] = wx1 * wy0 * wz0;  w[5] = wx1 * wy0 * wz1;
    w[6] = wx1 * wy1 * wz0;  w[7] = wx1 * wy1 * wz1;
}

// ---- pair setup (fp16 field passes): 4 (x,y) corners, z handled in-reg --
__device__ __forceinline__ void tri_setup_pair(
    int x, int y, int z, float fx, float fy, float fz,
    int* offp, float* wxy, float& wz0, float& wz1)
{
    float lx = fminf(fmaxf((float)x + fx, 0.0f), 127.0f);
    float ly = fminf(fmaxf((float)y + fy, 0.0f), 127.0f);
    float lz = fminf(fmaxf((float)z + fz, 0.0f), 127.0f);

    float flx = floorf(lx), fly = floorf(ly), flz = floorf(lz);
    float wx1 = lx - flx, wy1 = ly - fly;
    wz1 = lz - flz;                      // == 0 exactly when z0 == 127
    float wx0 = 1.0f - wx1, wy0 = 1.0f - wy1;
    wz0 = 1.0f - wz1;

    int x0 = (int)flx, y0 = (int)fly, z0 = (int)flz;
    int x1 = min(x0 + 1, 127);
    int y1 = min(y0 + 1, 127);

    offp[0] = (x0 << 14) + (y0 << 7) + z0;
    offp[1] = (x0 << 14) + (y1 << 7) + z0;
    offp[2] = (x1 << 14) + (y0 << 7) + z0;
    offp[3] = (x1 << 14) + (y1 << 7) + z0;
    wxy[0] = wx0 * wy0;  wxy[1] = wx0 * wy1;
    wxy[2] = wx1 * wy0;  wxy[3] = wx1 * wy1;
}

// batched 4x dwordx4 pair-gather + reduce
__device__ __forceinline__ void sample_pairs(
    const h16x4* __restrict__ vb, const int* offp, const float* wxy,
    float wz0, float wz1, float& ox, float& oy, float& oz)
{
    h16x8 c[4];
#pragma unroll
    for (int p = 0; p < 4; ++p)
        c[p] = *(const h16x8*)(vb + offp[p]);   // 8B-aligned dwordx4

    ox = 0.0f; oy = 0.0f; oz = 0.0f;
#pragma unroll
    for (int p = 0; p < 4; ++p) {
        float sx = wz0 * (float)c[p][0] + wz1 * (float)c[p][4];
        float sy = wz0 * (float)c[p][1] + wz1 * (float)c[p][5];
        float sz = wz0 * (float)c[p][2] + wz1 * (float)c[p][6];
        ox += wxy[p] * sx;
        oy += wxy[p] * sy;
        oz += wxy[p] * sz;
    }
}

// ---- step 1: f32 packed vel -> fp16x4 field (fuses the /128 scale) -----
__global__ __launch_bounds__(256, 4) void vecint_first(
    const float* __restrict__ vin, h16x4* __restrict__ vout,
    float scale, int nvox)
{
    int idx = swz_idx();
    if (idx >= nvox) return;

    int z = idx & 127;
    int y = (idx >> 7) & 127;
    int x = (idx >> 14) & 127;
    int b = idx >> 21;

    int base = idx * 3;
    float fx = vin[base + 0] * scale;
    float fy = vin[base + 1] * scale;
    float fz = vin[base + 2] * scale;

    int off[8]; float w[8];
    tri_setup(x, y, z, fx, fy, fz, off, w);

    const float* vb = vin + (size_t)b * (NVOX_PER_B * 3);

    // gather phase: all 24 dword loads issued before any use
    float c[8][3];
#pragma unroll
    for (int i = 0; i < 8; ++i) {
        const float* p = vb + (size_t)off[i] * 3;
        c[i][0] = p[0]; c[i][1] = p[1]; c[i][2] = p[2];
    }

    float ox = 0.0f, oy = 0.0f, oz = 0.0f;
#pragma unroll
    for (int i = 0; i < 8; ++i) {
        ox += w[i] * c[i][0]; oy += w[i] * c[i][1]; oz += w[i] * c[i][2];
    }

    h16x4 o;
    o.x = (h16)(fx + scale * ox);
    o.y = (h16)(fy + scale * oy);
    o.z = (h16)(fz + scale * oz);
    o.w = (h16)0.0f;
    vout[idx] = o;
}

// ---- steps 2..6: fp16x4 -> fp16x4 --------------------------------------
__global__ __launch_bounds__(256, 4) void vecint_mid(
    const h16x4* __restrict__ vin, h16x4* __restrict__ vout, int nvox)
{
    int idx = swz_idx();
    if (idx >= nvox) return;

    int z = idx & 127;
    int y = (idx >> 7) & 127;
    int x = (idx >> 14) & 127;
    int b = idx >> 21;

    h16x4 f = vin[idx];
    float fx = (float)f.x, fy = (float)f.y, fz = (float)f.z;

    int offp[4]; float wxy[4], wz0, wz1;
    tri_setup_pair(x, y, z, fx, fy, fz, offp, wxy, wz0, wz1);

    const h16x4* vb = vin + ((size_t)b << 21);
    float ox, oy, oz;
    sample_pairs(vb, offp, wxy, wz0, wz1, ox, oy, oz);

    h16x4 o;
    o.x = (h16)(fx + ox);
    o.y = (h16)(fy + oy);
    o.z = (h16)(fz + oz);
    o.w = (h16)0.0f;
    vout[idx] = o;
}

// ---- step 7: fp16x4 -> f32 packed --------------------------------------
__global__ __launch_bounds__(256, 4) void vecint_last(
    const h16x4* __restrict__ vin, float* __restrict__ vout, int nvox)
{
    int idx = swz_idx();
    if (idx >= nvox) return;

    int z = idx & 127;
    int y = (idx >> 7) & 127;
    int x = (idx >> 14) & 127;
    int b = idx >> 21;

    h16x4 f = vin[idx];
    float fx = (float)f.x, fy = (float)f.y, fz = (float)f.z;

    int offp[4]; float wxy[4], wz0, wz1;
    tri_setup_pair(x, y, z, fx, fy, fz, offp, wxy, wz0, wz1);

    const h16x4* vb = vin + ((size_t)b << 21);
    float ox, oy, oz;
    sample_pairs(vb, offp, wxy, wz0, wz1, ox, oy, oz);

    int base = idx * 3;
    vout[base + 0] = fx + ox;
    vout[base + 1] = fy + oy;
    vout[base + 2] = fz + oz;
}

extern "C" void kernel_launch(void* const* d_in, const int* in_sizes, int n_in,
                              void* d_out, int out_size, void* d_ws, size_t ws_size,
                              hipStream_t stream) {
    const float* vel = (const float*)d_in[0];
    float* out = (float*)d_out;

    int nvox = in_sizes[0] / 3;            // 4,194,304 voxels (2 batches)
    int blocks = (nvox + 255) / 256;       // 16384 (divisible by 8)
    float s0 = 1.0f / 128.0f;              // 1 / 2^INT_STEPS

    // D = fp16 field living in the first 33.5 MB of d_out (d_out is 50.3 MB);
    // W = fp16 field in d_ws.
    h16x4* D = (h16x4*)d_out;
    h16x4* W = (h16x4*)d_ws;

    // zero 16B past each field so the z-pair load's weight-0 hi half can
    // never read NaN bits at the absolute last voxel (stays inside the
    // 50.3MB allocations; graph-capture-safe async op)
    hipMemsetAsync((char*)d_out + (size_t)nvox * 8, 0, 16, stream);
    hipMemsetAsync((char*)d_ws  + (size_t)nvox * 8, 0, 16, stream);

    vecint_first<<<blocks, 256, 0, stream>>>(vel, D, s0, nvox);   // 1: vel->D
    vecint_mid  <<<blocks, 256, 0, stream>>>(D, W, nvox);         // 2: D->W
    vecint_mid  <<<blocks, 256, 0, stream>>>(W, D, nvox);         // 3: W->D
    vecint_mid  <<<blocks, 256, 0, stream>>>(D, W, nvox);         // 4: D->W
    vecint_mid  <<<blocks, 256, 0, stream>>>(W, D, nvox);         // 5: W->D
    vecint_mid  <<<blocks, 256, 0, stream>>>(D, W, nvox);         // 6: D->W
    vecint_last <<<blocks, 256, 0, stream>>>(W, out, nvox);       // 7: W->out (f32)
}

// Round 4
// 264.791 us; speedup vs baseline: 1.1688x; 1.0043x over previous
//
#include <hip/hip_runtime.h>

// VecInt: scaling-and-squaring integration, vel [2,128,128,128,3] fp32.
// v = vel/2^7; 7x: v = v + warp(v, v)  (border-clipped trilinear).
//
// Round-9: r8 skeleton + FORCED gather batching via sched_barrier(0).
// Evidence trail:
//   r6: time scales ~1/resident_waves (occ 43% -> 1.47x slower) => latency-bound.
//   r7: gathers L3->L2 (FETCH halved) => time FLAT => per-epoch latency is
//       queueing, not tier; only epoch COUNT and wave count matter.
//   r8: source-level load-all-then-reduce did NOT batch: VGPR stayed 28,
//       compiler's reg-minimizing scheduler re-interleaved load->use =>
//       ~4-8 serialized epochs/thread survived. Win was only 289->266.
// Fix: __builtin_amdgcn_sched_barrier(0) between the gather loads and the
// reduce -- nothing may cross it, so ALL loads issue first (one wait epoch).
// VGPR deliberately rises to hold the batch; launch_bounds keeps 8 (mid) /
// 6 (first) blocks/CU so occupancy stays high.

#define NVOX_PER_B (1 << 21)          // 128^3
#define NXCD 8

typedef _Float16 h16;
typedef __attribute__((ext_vector_type(4))) _Float16 h16x4;   // 8 bytes
typedef __attribute__((ext_vector_type(8))) _Float16 h16x8;   // 16 bytes

__device__ __forceinline__ int swz_idx()
{
    // chunked XCD swizzle: contiguous 1/8 of the grid per XCD (16384%8==0)
    int nb = gridDim.x;
    int chunk = nb >> 3;
    int bid = blockIdx.x;
    int newbid = (bid & (NXCD - 1)) * chunk + (bid >> 3);
    return newbid * blockDim.x + threadIdx.x;
}

// ---- full 8-corner setup (f32 first pass) ------------------------------
__device__ __forceinline__ void tri_setup(
    int x, int y, int z, float fx, float fy, float fz,
    int* off, float* w)
{
    float lx = fminf(fmaxf((float)x + fx, 0.0f), 127.0f);
    float ly = fminf(fmaxf((float)y + fy, 0.0f), 127.0f);
    float lz = fminf(fmaxf((float)z + fz, 0.0f), 127.0f);

    float flx = floorf(lx), fly = floorf(ly), flz = floorf(lz);
    float wx1 = lx - flx, wy1 = ly - fly, wz1 = lz - flz;
    float wx0 = 1.0f - wx1, wy0 = 1.0f - wy1, wz0 = 1.0f - wz1;

    int x0 = (int)flx, y0 = (int)fly, z0 = (int)flz;
    int x1 = min(x0 + 1, 127);
    int y1 = min(y0 + 1, 127);
    int z1 = min(z0 + 1, 127);

    off[0] = (x0 << 14) + (y0 << 7) + z0;
    off[1] = (x0 << 14) + (y0 << 7) + z1;
    off[2] = (x0 << 14) + (y1 << 7) + z0;
    off[3] = (x0 << 14) + (y1 << 7) + z1;
    off[4] = (x1 << 14) + (y0 << 7) + z0;
    off[5] = (x1 << 14) + (y0 << 7) + z1;
    off[6] = (x1 << 14) + (y1 << 7) + z0;
    off[7] = (x1 << 14) + (y1 << 7) + z1;
    w[0] = wx0 * wy0 * wz0;  w[1] = wx0 * wy0 * wz1;
    w[2] = wx0 * wy1 * wz0;  w[3] = wx0 * wy1 * wz1;
    w[4] = wx1 * wy0 * wz0;  w[5] = wx1 * wy0 * wz1;
    w[6] = wx1 * wy1 * wz0;  w[7] = wx1 * wy1 * wz1;
}

// ---- pair setup (fp16 field passes): 4 (x,y) corners, z handled in-reg --
__device__ __forceinline__ void tri_setup_pair(
    int x, int y, int z, float fx, float fy, float fz,
    int* offp, float* wxy, float& wz0, float& wz1)
{
    float lx = fminf(fmaxf((float)x + fx, 0.0f), 127.0f);
    float ly = fminf(fmaxf((float)y + fy, 0.0f), 127.0f);
    float lz = fminf(fmaxf((float)z + fz, 0.0f), 127.0f);

    float flx = floorf(lx), fly = floorf(ly), flz = floorf(lz);
    float wx1 = lx - flx, wy1 = ly - fly;
    wz1 = lz - flz;                      // == 0 exactly when z0 == 127
    float wx0 = 1.0f - wx1, wy0 = 1.0f - wy1;
    wz0 = 1.0f - wz1;

    int x0 = (int)flx, y0 = (int)fly, z0 = (int)flz;
    int x1 = min(x0 + 1, 127);
    int y1 = min(y0 + 1, 127);

    offp[0] = (x0 << 14) + (y0 << 7) + z0;
    offp[1] = (x0 << 14) + (y1 << 7) + z0;
    offp[2] = (x1 << 14) + (y0 << 7) + z0;
    offp[3] = (x1 << 14) + (y1 << 7) + z0;
    wxy[0] = wx0 * wy0;  wxy[1] = wx0 * wy1;
    wxy[2] = wx1 * wy0;  wxy[3] = wx1 * wy1;
}

// batched 4x dwordx4 pair-gather + reduce; sched_barrier forces all 4
// loads to issue before any consumer (one wait epoch).
__device__ __forceinline__ void sample_pairs(
    const h16x4* __restrict__ vb, const int* offp, const float* wxy,
    float wz0, float wz1, float& ox, float& oy, float& oz)
{
    h16x8 c0 = *(const h16x8*)(vb + offp[0]);
    h16x8 c1 = *(const h16x8*)(vb + offp[1]);
    h16x8 c2 = *(const h16x8*)(vb + offp[2]);
    h16x8 c3 = *(const h16x8*)(vb + offp[3]);
    __builtin_amdgcn_sched_barrier(0);   // loads above, math below

    float sx0 = wz0 * (float)c0[0] + wz1 * (float)c0[4];
    float sy0 = wz0 * (float)c0[1] + wz1 * (float)c0[5];
    float sz0 = wz0 * (float)c0[2] + wz1 * (float)c0[6];
    float sx1 = wz0 * (float)c1[0] + wz1 * (float)c1[4];
    float sy1 = wz0 * (float)c1[1] + wz1 * (float)c1[5];
    float sz1 = wz0 * (float)c1[2] + wz1 * (float)c1[6];
    float sx2 = wz0 * (float)c2[0] + wz1 * (float)c2[4];
    float sy2 = wz0 * (float)c2[1] + wz1 * (float)c2[5];
    float sz2 = wz0 * (float)c2[2] + wz1 * (float)c2[6];
    float sx3 = wz0 * (float)c3[0] + wz1 * (float)c3[4];
    float sy3 = wz0 * (float)c3[1] + wz1 * (float)c3[5];
    float sz3 = wz0 * (float)c3[2] + wz1 * (float)c3[6];

    ox = wxy[0] * sx0 + wxy[1] * sx1 + wxy[2] * sx2 + wxy[3] * sx3;
    oy = wxy[0] * sy0 + wxy[1] * sy1 + wxy[2] * sy2 + wxy[3] * sy3;
    oz = wxy[0] * sz0 + wxy[1] * sz1 + wxy[2] * sz2 + wxy[3] * sz3;
}

// ---- step 1: f32 packed vel -> fp16x4 field (fuses the /128 scale) -----
__global__ __launch_bounds__(256, 6) void vecint_first(
    const float* __restrict__ vin, h16x4* __restrict__ vout,
    float scale, int nvox)
{
    int idx = swz_idx();
    if (idx >= nvox) return;

    int z = idx & 127;
    int y = (idx >> 7) & 127;
    int x = (idx >> 14) & 127;
    int b = idx >> 21;

    int base = idx * 3;
    float fx = vin[base + 0] * scale;
    float fy = vin[base + 1] * scale;
    float fz = vin[base + 2] * scale;

    int off[8]; float w[8];
    tri_setup(x, y, z, fx, fy, fz, off, w);

    const float* vb = vin + (size_t)b * (NVOX_PER_B * 3);

    // gather phase: all 24 dword loads issued, then a hard scheduler fence
    float c[8][3];
#pragma unroll
    for (int i = 0; i < 8; ++i) {
        const float* p = vb + (size_t)off[i] * 3;
        c[i][0] = p[0]; c[i][1] = p[1]; c[i][2] = p[2];
    }
    __builtin_amdgcn_sched_barrier(0);

    float ox = 0.0f, oy = 0.0f, oz = 0.0f;
#pragma unroll
    for (int i = 0; i < 8; ++i) {
        ox += w[i] * c[i][0]; oy += w[i] * c[i][1]; oz += w[i] * c[i][2];
    }

    h16x4 o;
    o.x = (h16)(fx + scale * ox);
    o.y = (h16)(fy + scale * oy);
    o.z = (h16)(fz + scale * oz);
    o.w = (h16)0.0f;
    vout[idx] = o;
}

// ---- steps 2..6: fp16x4 -> fp16x4 --------------------------------------
__global__ __launch_bounds__(256, 8) void vecint_mid(
    const h16x4* __restrict__ vin, h16x4* __restrict__ vout, int nvox)
{
    int idx = swz_idx();
    if (idx >= nvox) return;

    int z = idx & 127;
    int y = (idx >> 7) & 127;
    int x = (idx >> 14) & 127;
    int b = idx >> 21;

    h16x4 f = vin[idx];
    float fx = (float)f.x, fy = (float)f.y, fz = (float)f.z;

    int offp[4]; float wxy[4], wz0, wz1;
    tri_setup_pair(x, y, z, fx, fy, fz, offp, wxy, wz0, wz1);

    const h16x4* vb = vin + ((size_t)b << 21);
    float ox, oy, oz;
    sample_pairs(vb, offp, wxy, wz0, wz1, ox, oy, oz);

    h16x4 o;
    o.x = (h16)(fx + ox);
    o.y = (h16)(fy + oy);
    o.z = (h16)(fz + oz);
    o.w = (h16)0.0f;
    vout[idx] = o;
}

// ---- step 7: fp16x4 -> f32 packed --------------------------------------
__global__ __launch_bounds__(256, 8) void vecint_last(
    const h16x4* __restrict__ vin, float* __restrict__ vout, int nvox)
{
    int idx = swz_idx();
    if (idx >= nvox) return;

    int z = idx & 127;
    int y = (idx >> 7) & 127;
    int x = (idx >> 14) & 127;
    int b = idx >> 21;

    h16x4 f = vin[idx];
    float fx = (float)f.x, fy = (float)f.y, fz = (float)f.z;

    int offp[4]; float wxy[4], wz0, wz1;
    tri_setup_pair(x, y, z, fx, fy, fz, offp, wxy, wz0, wz1);

    const h16x4* vb = vin + ((size_t)b << 21);
    float ox, oy, oz;
    sample_pairs(vb, offp, wxy, wz0, wz1, ox, oy, oz);

    int base = idx * 3;
    vout[base + 0] = fx + ox;
    vout[base + 1] = fy + oy;
    vout[base + 2] = fz + oz;
}

extern "C" void kernel_launch(void* const* d_in, const int* in_sizes, int n_in,
                              void* d_out, int out_size, void* d_ws, size_t ws_size,
                              hipStream_t stream) {
    const float* vel = (const float*)d_in[0];
    float* out = (float*)d_out;

    int nvox = in_sizes[0] / 3;            // 4,194,304 voxels (2 batches)
    int blocks = (nvox + 255) / 256;       // 16384 (divisible by 8)
    float s0 = 1.0f / 128.0f;              // 1 / 2^INT_STEPS

    // D = fp16 field living in the first 33.5 MB of d_out (d_out is 50.3 MB);
    // W = fp16 field in d_ws.
    h16x4* D = (h16x4*)d_out;
    h16x4* W = (h16x4*)d_ws;

    // zero 16B past each field so the z-pair load's weight-0 hi half can
    // never read NaN bits at the absolute last voxel (stays inside the
    // 50.3MB allocations; graph-capture-safe async op)
    hipMemsetAsync((char*)d_out + (size_t)nvox * 8, 0, 16, stream);
    hipMemsetAsync((char*)d_ws  + (size_t)nvox * 8, 0, 16, stream);

    vecint_first<<<blocks, 256, 0, stream>>>(vel, D, s0, nvox);   // 1: vel->D
    vecint_mid  <<<blocks, 256, 0, stream>>>(D, W, nvox);         // 2: D->W
    vecint_mid  <<<blocks, 256, 0, stream>>>(W, D, nvox);         // 3: W->D
    vecint_mid  <<<blocks, 256, 0, stream>>>(D, W, nvox);         // 4: D->W
    vecint_mid  <<<blocks, 256, 0, stream>>>(W, D, nvox);         // 5: W->D
    vecint_mid  <<<blocks, 256, 0, stream>>>(D, W, nvox);         // 6: D->W
    vecint_last <<<blocks, 256, 0, stream>>>(W, out, nvox);       // 7: W->out (f32)
}